// Round 19
// baseline (187.844 us; speedup 1.0000x reference)
//
#include <hip/hip_runtime.h>
#include <cstddef>

typedef float f32x4 __attribute__((ext_vector_type(4)));
typedef __bf16 bf16x8 __attribute__((ext_vector_type(8)));
typedef unsigned short u16;
typedef unsigned short u16x4 __attribute__((ext_vector_type(4)));

__device__ __forceinline__ u16 f2bf(float f) {
  unsigned u = __builtin_bit_cast(unsigned, f);
  u += 0x7FFFu + ((u >> 16) & 1u);   // RNE round to bf16
  return (u16)(u >> 16);
}
__device__ __forceinline__ float bf2f(u16 b) {
  unsigned u = ((unsigned)b) << 16;
  return __builtin_bit_cast(float, u);
}
__device__ __forceinline__ u16 cvt_bf(float f) {   // native RNE cast
  return __builtin_bit_cast(u16, (__bf16)f);
}
__device__ __forceinline__ float fastrcp(float x) { return __builtin_amdgcn_rcpf(x); }
#if __has_builtin(__builtin_amdgcn_exp2f)
__device__ __forceinline__ float fexp2(float x) { return __builtin_amdgcn_exp2f(x); }
#else
__device__ __forceinline__ float fexp2(float x) { return exp2f(x); }
#endif
#define LOG2E 1.44269504f
#define LOG2E2 2.88539008f

__device__ __forceinline__ void wg_barrier() {
  asm volatile("s_waitcnt lgkmcnt(0)" ::: "memory");
  __builtin_amdgcn_s_barrier();
  __builtin_amdgcn_sched_barrier(0);
}

// ---------------------------------------------------------------------------
// K1 v4 (R18, proven): 64m x 64n per wg, K split 2x160, B-prefetch pipeline.
// ---------------------------------------------------------------------------
#define K1S 168

#define K1_ISSUE_B(C_, KH_)                                                 \
  {                                                                         \
    const int nc_ = z * 4 + (C_);                                           \
    _Pragma("unroll")                                                       \
    for (int it = 0; it < 10; ++it) {                                       \
      const int idx = it * 256 + tid;                                       \
      const int row = idx / 40, kq = idx % 40;                              \
      const int k = (KH_) * 160 + kq * 4;                                   \
      const int j = nc_ * 16 + (row & 15);                                  \
      const int n = (row >> 4) * 100 + j;                                   \
      const bool val = (k < 300 && j < 100);                                \
      const long o_ = val ? ((long)n * 300 + k) : 0;                        \
      breg[it] = *(const f32x4*)(wih + o_);                                 \
    }                                                                       \
  }

#define K1_WRITE_B(C_, KH_)                                                 \
  {                                                                         \
    const int nc_ = z * 4 + (C_);                                           \
    _Pragma("unroll")                                                       \
    for (int it = 0; it < 10; ++it) {                                       \
      const int idx = it * 256 + tid;                                       \
      const int row = idx / 40, kq = idx % 40;                              \
      const int k = (KH_) * 160 + kq * 4;                                   \
      const int j = nc_ * 16 + (row & 15);                                  \
      u16x4 o = {0, 0, 0, 0};                                               \
      if (k < 300 && j < 100) {                                             \
        o[0] = cvt_bf(breg[it][0]); o[1] = cvt_bf(breg[it][1]);             \
        o[2] = cvt_bf(breg[it][2]); o[3] = cvt_bf(breg[it][3]);             \
      }                                                                     \
      *(u16x4*)(bL + row * K1S + kq * 4) = o;                               \
    }                                                                       \
  }

#define K1_MFMA(KH_)                                                        \
  {                                                                         \
    const u16* ak = a0 + (KH_) * 64 * K1S;                                  \
    _Pragma("unroll")                                                       \
    for (int ks = 0; ks < 5; ++ks) {                                        \
      const bf16x8 af = *(const bf16x8*)(ak + ks * 32);                     \
      bf16x8 bfv[4];                                                        \
      _Pragma("unroll")                                                     \
      for (int nt = 0; nt < 4; ++nt)                                        \
        bfv[nt] = *(const bf16x8*)(b0 + nt * 16 * K1S + ks * 32);           \
      _Pragma("unroll")                                                     \
      for (int nt = 0; nt < 4; ++nt)                                        \
        acc[nt] = __builtin_amdgcn_mfma_f32_16x16x32_bf16(af, bfv[nt], acc[nt], 0, 0, 0); \
    }                                                                       \
  }

__global__ __launch_bounds__(256) void k1_xproj(
    const int* __restrict__ tok1, const int* __restrict__ tok2,
    const float* __restrict__ embed,
    const float* __restrict__ wihA, const float* __restrict__ wihB,
    const float* __restrict__ wihC, const float* __restrict__ wihD,
    const float* __restrict__ bihA, const float* __restrict__ bihB,
    const float* __restrict__ bihC, const float* __restrict__ bihD,
    const float* __restrict__ bhhA, const float* __restrict__ bhhB,
    const float* __restrict__ bhhC, const float* __restrict__ bhhD,
    float* __restrict__ xprojP)
{
  __shared__ __align__(16) u16 aL[2 * 64 * K1S];   // 43.0 KB
  __shared__ __align__(16) u16 bL[64 * K1S];       // 21.5 KB
  __shared__ __align__(16) float tp[4096];         // 16.0 KB
  const int mg = blockIdx.x;
  const int dir = blockIdx.y;
  const int z = blockIdx.z;
  const float* wih = (dir == 0) ? wihA : (dir == 1) ? wihB : (dir == 2) ? wihC : wihD;
  const float* bih = (dir == 0) ? bihA : (dir == 1) ? bihB : (dir == 2) ? bihC : bihD;
  const float* bhh = (dir == 0) ? bhhA : (dir == 1) ? bhhB : (dir == 2) ? bhhC : bhhD;
  const int* tok = (dir < 2) ? tok1 : tok2;
  const int tid = threadIdx.x;

  f32x4 breg[10];
  K1_ISSUE_B(0, 0)

  #pragma unroll
  for (int it = 0; it < 20; ++it) {
    const int idx = it * 256 + tid;
    const int row = idx / 80, k = (idx % 80) * 4;
    u16x4 o = {0, 0, 0, 0};
    if (k < 300) {
      const int bb = row & 31, ll = mg * 2 + (row >> 5);
      const long ar = (long)tok[bb * 128 + ll] * 300;
      const f32x4 v = *(const f32x4*)(embed + ar + k);
      o[0] = cvt_bf(v[0]); o[1] = cvt_bf(v[1]); o[2] = cvt_bf(v[2]); o[3] = cvt_bf(v[3]);
    }
    const int kh = k >= 160;
    *(u16x4*)(aL + kh * 64 * K1S + row * K1S + (k - kh * 160)) = o;
  }

  const int lane = tid & 63, w = tid >> 6;
  const int lr = lane & 15, kg = lane >> 4;
  const int lloc = w >> 1;
  const int bloc0 = (w & 1) * 16 + kg * 4;
  const u16* a0 = aL + (w * 16 + lr) * K1S + kg * 8;
  const u16* b0 = bL + lr * K1S + kg * 8;
  const int nch = z ? 3 : 4;

  for (int c = 0; c < nch; ++c) {
    const int nc = z * 4 + c;
    f32x4 acc[4];
    #pragma unroll
    for (int nt = 0; nt < 4; ++nt) acc[nt] = 0.f;

    __syncthreads();
    K1_WRITE_B(c, 0)
    K1_ISSUE_B(c, 1)
    __syncthreads();
    K1_MFMA(0)
    __syncthreads();
    K1_WRITE_B(c, 1)
    if (c + 1 < nch) { K1_ISSUE_B(c + 1, 0) }
    __syncthreads();
    K1_MFMA(1)

    const int jl = nc * 16 + lr;
    float bias[4];
    #pragma unroll
    for (int nt = 0; nt < 4; ++nt)
      bias[nt] = (jl < 100) ? (bih[nt * 100 + jl] + bhh[nt * 100 + jl]) : 0.f;
    #pragma unroll
    for (int rr = 0; rr < 4; ++rr) {
      f32x4 v;
      v[0] = (acc[0][rr] + bias[0]) * LOG2E;
      v[1] = (acc[1][rr] + bias[1]) * LOG2E;
      v[2] = (acc[2][rr] + bias[2]) * LOG2E2;
      v[3] = (acc[3][rr] + bias[3]) * LOG2E;
      const int gran = (lloc * 16 + lr) * 32 + bloc0 + rr;
      *(f32x4*)(tp + gran * 4) = v;
    }
    __syncthreads();

    #pragma unroll
    for (int it = 0; it < 4; ++it) {
      const int idx = it * 256 + tid;
      const int sl = idx >> 9, j = (idx >> 5) & 15, b = idx & 31;
      const int jg = nc * 16 + j;
      const f32x4 v = *(const f32x4*)(tp + idx * 4);
      if (jg < 100)
        *(f32x4*)(xprojP + ((long)(dir * 128 + mg * 2 + sl) * 100 + jg) * 128 + b * 4) = v;
    }
  }
}

// ---------------------------------------------------------------------------
// K2: recurrent LSTM, 10 WAVES (640 thr): wave w owns m-tiles {w, w+10, w+20}
//   -> max 3 tile-chains/wave (was 4 on wave 0 of 8): straggler cut 25%.
//   Unroll-by-4 named prefetch sets, 1 lgkm-barrier/step, coalesced copy.
// ---------------------------------------------------------------------------
__device__ __forceinline__ bf16x8 frag_ld(const float* __restrict__ whh,
                                          int mt, int ks, int lr, int kg) {
  bf16x8 f;
  const int orow = (lr & 3) * 100 + mt * 4 + (lr >> 2);
  const float sc = ((lr & 3) == 2) ? LOG2E2 : LOG2E;
  #pragma unroll
  for (int u = 0; u < 8; ++u) {
    const int k = ks * 32 + kg * 8 + u;
    const float v = (mt < 25 && k < 100) ? whh[(long)orow * 100 + k] : 0.f;
    f[u] = (__bf16)(v * sc);
  }
  return f;
}

#define K2_MFMA4(A_, C_, F0_, F1_, F2_, F3_)                                \
  A_ = __builtin_amdgcn_mfma_f32_16x16x32_bf16(F0_, hb0, C_, 0, 0, 0);      \
  A_ = __builtin_amdgcn_mfma_f32_16x16x32_bf16(F1_, hb1, A_, 0, 0, 0);      \
  A_ = __builtin_amdgcn_mfma_f32_16x16x32_bf16(F2_, hb2, A_, 0, 0, 0);      \
  A_ = __builtin_amdgcn_mfma_f32_16x16x32_bf16(F3_, hb3, A_, 0, 0, 0);

#define K2_GATE(A_, CC_, WRO_, WBUF_)                                       \
  {                                                                         \
    const float Ei = fexp2(A_[0]);                                          \
    const float Ef = fexp2(A_[1]);                                          \
    const float Eg = fexp2(A_[2]);                                          \
    const float pf = 1.0f + Ef, pi = 1.0f + Ei, pg = Eg + 1.0f;             \
    const float d_ = fastrcp(pf * pi * pg);                                 \
    CC_ = (Ef * CC_ * pi * pg + Ei * (Eg - 1.0f) * pf) * d_;                \
    const float Eo = fexp2(A_[3]);                                          \
    const float Ec = fexp2(CC_ * LOG2E2);                                   \
    const float h_ = Eo * (Ec - 1.0f) * fastrcp((1.0f + Eo) * (Ec + 1.0f)); \
    *(u16*)(hby + (WRO_) + (WBUF_) * 4096) = f2bf(h_);                      \
  }

// step: reads h buf RB_, writes buf RB_^1; consumes XC0..2, prefetches t+2
// into XP0..2. Tiles 0,1 unconditional; tile 2 only when act2 (wave < 5).
#define K2_STEP(RB_, XC0, XC1, XC2, XP0, XP1, XP2)                          \
  {                                                                         \
    bf16x8 hb0 = *(const bf16x8*)(hby + rd0 + (RB_) * 4096);                \
    bf16x8 hb1 = *(const bf16x8*)(hby + rd1 + (RB_) * 4096);                \
    bf16x8 hb2 = *(const bf16x8*)(hby + rd2 + (RB_) * 4096);                \
    bf16x8 hb3 = *(const bf16x8*)(hby + rd3 + (RB_) * 4096);                \
    XP0 = *(const f32x4*)(pstep + off0);                                    \
    XP1 = *(const f32x4*)(pstep + off1);                                    \
    if (act2) XP2 = *(const f32x4*)(pstep + off2);                          \
    pstep += dstep;                                                         \
    f32x4 a0, a1, a2;                                                       \
    K2_MFMA4(a0, XC0, f00, f01, f02, f03)                                   \
    K2_MFMA4(a1, XC1, f10, f11, f12, f13)                                   \
    if (act2) { K2_MFMA4(a2, XC2, f20, f21, f22, f23) }                     \
    K2_GATE(a0, cc0, wr0, (RB_) ^ 1)                                        \
    K2_GATE(a1, cc1, wr1, (RB_) ^ 1)                                        \
    if (act2) { K2_GATE(a2, cc2, wr2, (RB_) ^ 1) }                          \
  }

#define K2_COPY(TA_, CB_)                                                   \
  if (cact) {                                                               \
    const unsigned v_ = *(const unsigned*)(hby + cprd + (CB_) * 4096);      \
    const unsigned v2_ = *(const unsigned*)(hby + cprd + 2048 + (CB_) * 4096); \
    seD[cpbase + (TA_) * 100] = v_;                                         \
    seD[cpbase2 + (TA_) * 100] = v2_;                                       \
  }

__global__ __launch_bounds__(640, 1) void k2_lstm(
    const float* __restrict__ xprojP,
    const float* __restrict__ whhA, const float* __restrict__ whhB,
    const float* __restrict__ whhC, const float* __restrict__ whhD,
    u16* __restrict__ s1e, u16* __restrict__ s2e)
{
  const int bh = blockIdx.x;
  const int dir = blockIdx.y;
  const float* whh = (dir == 0) ? whhA : (dir == 1) ? whhB : (dir == 2) ? whhC : whhD;
  const int tid = threadIdx.x;
  const int lane = tid & 63, wave = tid >> 6;       // wave 0..9
  const int lr = lane & 15, kg = lane >> 4;
  const int mt0 = wave, mt1 = wave + 10, mt2 = wave + 20;
  const bool act2 = (mt2 < 25);                     // waves 0..4

  __shared__ __align__(16) u16 hraw[2 * 16 * 128];
  char* hby = (char*)hraw;

  bf16x8 f00 = frag_ld(whh, mt0, 0, lr, kg), f01 = frag_ld(whh, mt0, 1, lr, kg),
         f02 = frag_ld(whh, mt0, 2, lr, kg), f03 = frag_ld(whh, mt0, 3, lr, kg);
  bf16x8 f10 = frag_ld(whh, mt1, 0, lr, kg), f11 = frag_ld(whh, mt1, 1, lr, kg),
         f12 = frag_ld(whh, mt1, 2, lr, kg), f13 = frag_ld(whh, mt1, 3, lr, kg);
  bf16x8 f20 = frag_ld(whh, mt2, 0, lr, kg), f21 = frag_ld(whh, mt2, 1, lr, kg),
         f22 = frag_ld(whh, mt2, 2, lr, kg), f23 = frag_ld(whh, mt2, 3, lr, kg);

  for (int idx = tid; idx < 2 * 16 * 128; idx += 640) hraw[idx] = 0;

  const int e7 = lr & 7;
  const int rd0 = lr * 256 + ((kg ^ e7) * 16);
  const int rd1 = lr * 256 + (((4 + kg) ^ e7) * 16);
  const int rd2 = lr * 256 + (((8 + kg) ^ e7) * 16);
  const int rd3 = lr * 256 + (((12 + kg) ^ e7) * 16);
  const int wr0 = lr * 256 + (((mt0 >> 1) ^ e7) * 16) + ((mt0 & 1) * 4 + kg) * 2;
  const int wr1 = lr * 256 + (((mt1 >> 1) ^ e7) * 16) + ((mt1 & 1) * 4 + kg) * 2;
  const int wr2 = lr * 256 + (((mt2 >> 1) ^ e7) * 16) + ((mt2 & 1) * 4 + kg) * 2;

  const bool cact = (tid < 400);
  const int cb = tid / 50, cj2 = tid - cb * 50;
  const int cprd = cb * 256 + (((cj2 >> 2) ^ (cb & 7)) * 16) + (cj2 & 3) * 4;
  const bool bwd = (dir & 1);
  unsigned* seD = (unsigned*)((dir < 2) ? s1e : s2e);
  const long cpbase = ((long)(bh * 16 + cb) * 128) * 100 + (bwd ? 50 : 0) + cj2;
  const long cpbase2 = cpbase + (long)8 * 128 * 100;

  const float* pbase = xprojP + (long)dir * 128 * 12800;
  const int off0 = ((mt0 * 4 + kg) * 32 + bh * 16 + lr) * 4;
  const int off1 = ((mt1 * 4 + kg) * 32 + bh * 16 + lr) * 4;
  const int off2 = act2 ? (((mt2 * 4 + kg) * 32 + bh * 16 + lr) * 4) : 0;
  const long dstep = bwd ? -12800 : 12800;
  const float* pstep = pbase + (long)(bwd ? 125 : 2) * 12800;

  f32x4 xa0, xa1, xa2, xb0, xb1, xb2;
  f32x4 xc0, xc1, xc2, xd0, xd1, xd2;
  {
    const float* p0 = pbase + (long)(bwd ? 127 : 0) * 12800;
    const float* p1 = pbase + (long)(bwd ? 126 : 1) * 12800;
    xa0 = *(const f32x4*)(p0 + off0); xa1 = *(const f32x4*)(p0 + off1);
    xb0 = *(const f32x4*)(p1 + off0); xb1 = *(const f32x4*)(p1 + off1);
    xa2 = xb2 = f32x4{0.f, 0.f, 0.f, 0.f};
    xc0 = xc1 = xc2 = f32x4{0.f, 0.f, 0.f, 0.f};
    xd0 = xd1 = xd2 = f32x4{0.f, 0.f, 0.f, 0.f};
    if (act2) { xa2 = *(const f32x4*)(p0 + off2); xb2 = *(const f32x4*)(p1 + off2); }
  }
  float cc0 = 0.f, cc1 = 0.f, cc2 = 0.f;
  __syncthreads();

  #pragma unroll 1
  for (int tt = 0; tt < 32; ++tt) {
    const int i0 = 4 * tt;
    K2_STEP(0, xa0, xa1, xa2, xc0, xc1, xc2)   // consume A, prefetch C
    wg_barrier();
    K2_COPY(bwd ? 127 - i0 : i0, 1)
    K2_STEP(1, xb0, xb1, xb2, xd0, xd1, xd2)   // consume B, prefetch D
    wg_barrier();
    K2_COPY(bwd ? 126 - i0 : i0 + 1, 0)
    K2_STEP(0, xc0, xc1, xc2, xa0, xa1, xa2)   // consume C, prefetch A
    wg_barrier();
    K2_COPY(bwd ? 125 - i0 : i0 + 2, 1)
    K2_STEP(1, xd0, xd1, xd2, xb0, xb1, xb2)   // consume D, prefetch B
    wg_barrier();
    K2_COPY(bwd ? 124 - i0 : i0 + 3, 0)
  }
}

// ---------------------------------------------------------------------------
// K4 v2 (R16, proven): matching + fused norms, K-split, 2 wg/CU.
// ---------------------------------------------------------------------------
#define K4S 136
__global__ __launch_bounds__(256, 2) void k4_match(
    const u16* __restrict__ s1e, const u16* __restrict__ s2e,
    const float* __restrict__ W1, const float* __restrict__ W2,
    float* __restrict__ out)
{
  __shared__ __align__(16) u16 aLb[128 * K4S];
  __shared__ __align__(16) u16 bLb[128 * K4S];
  __shared__ float rnuL[128], rnvL[128];
  __shared__ float redA[2][128], redB[2][128];
  const int b = blockIdx.x, p = blockIdx.y, w = blockIdx.z;
  const int tid = threadIdx.x;
  const float* Wp = (w ? W2 : W1) + p * 200;
  const u16* s1r = s1e + (long)b * 128 * 200;
  const u16* s2r = s2e + (long)b * 128 * 200;

  const int lane = tid & 63, wvid = tid >> 6;
  const int wr = wvid >> 1, wc = wvid & 1;
  const int lr = lane & 15, kg = lane >> 4;
  const u16* a0 = aLb + (64 * wr + lr) * K4S + kg * 8;
  const u16* b0 = bLb + (64 * wc + lr) * K4S + kg * 8;

  f32x4 acc[4][4];
  #pragma unroll
  for (int mt = 0; mt < 4; ++mt)
    #pragma unroll
    for (int nt = 0; nt < 4; ++nt) acc[mt][nt] = 0.f;
  float nacc = 0.f;
  const int nrow = tid & 127;
  const u16* nsrc = (tid < 128) ? (aLb + nrow * K4S) : (bLb + nrow * K4S);

  #pragma unroll
  for (int ch = 0; ch < 2; ++ch) {
    const int k0 = ch * 128;
    const int NQ = ch ? 24 : 32;
    for (int idx = tid; idx < 128 * NQ; idx += 256) {
      const int row = idx / NQ;
      const int kq = idx - row * NQ;
      const int k = k0 + kq * 4;
      u16x4 oa = {0, 0, 0, 0}, ob = {0, 0, 0, 0};
      if (k < 200) {
        const u16x4 sa = *(const u16x4*)(s1r + row * 200 + k);
        const u16x4 sb = *(const u16x4*)(s2r + row * 200 + k);
        const f32x4 wv = *(const f32x4*)(Wp + k);
        #pragma unroll
        for (int u = 0; u < 4; ++u) {
          oa[u] = cvt_bf(bf2f(sa[u]) * wv[u]);
          ob[u] = cvt_bf(bf2f(sb[u]) * wv[u]);
        }
      }
      *(u16x4*)(aLb + row * K4S + kq * 4) = oa;
      *(u16x4*)(bLb + row * K4S + kq * 4) = ob;
    }
    __syncthreads();

    {
      const int nq8 = ch ? 12 : 16;
      #pragma unroll 4
      for (int q = 0; q < nq8; ++q) {
        const bf16x8 v = *(const bf16x8*)(nsrc + q * 8);
        #pragma unroll
        for (int u = 0; u < 8; ++u) {
          const float f = (float)v[u];
          nacc += f * f;
        }
      }
    }
    const int nks = ch ? 3 : 4;
    for (int ks = 0; ks < nks; ++ks) {
      bf16x8 af[4], bfv[4];
      #pragma unroll
      for (int mt = 0; mt < 4; ++mt) af[mt] = *(const bf16x8*)(a0 + mt * 16 * K4S + ks * 32);
      #pragma unroll
      for (int nt = 0; nt < 4; ++nt) bfv[nt] = *(const bf16x8*)(b0 + nt * 16 * K4S + ks * 32);
      #pragma unroll
      for (int mt = 0; mt < 4; ++mt)
        #pragma unroll
        for (int nt = 0; nt < 4; ++nt)
          acc[mt][nt] = __builtin_amdgcn_mfma_f32_16x16x32_bf16(af[mt], bfv[nt], acc[mt][nt], 0, 0, 0);
    }
    __syncthreads();
  }

  {
    const float rv = 1.f / fmaxf(sqrtf(nacc), 1e-8f);
    if (tid < 128) rnuL[nrow] = rv; else rnvL[nrow] = rv;
  }
  __syncthreads();

  float ru[4][4], rm[4][4], rv[4], cm[4];
  #pragma unroll
  for (int mt = 0; mt < 4; ++mt)
    #pragma unroll
    for (int r = 0; r < 4; ++r) {
      ru[mt][r] = rnuL[64 * wr + mt * 16 + kg * 4 + r];
      rm[mt][r] = -3.0e38f;
    }
  #pragma unroll
  for (int nt = 0; nt < 4; ++nt) { rv[nt] = rnvL[64 * wc + nt * 16 + lr]; cm[nt] = -3.0e38f; }
  #pragma unroll
  for (int mt = 0; mt < 4; ++mt)
    #pragma unroll
    for (int nt = 0; nt < 4; ++nt)
      #pragma unroll
      for (int r = 0; r < 4; ++r) {
        const float v = acc[mt][nt][r] * ru[mt][r] * rv[nt];
        rm[mt][r] = fmaxf(rm[mt][r], v);
        cm[nt] = fmaxf(cm[nt], v);
      }
  #pragma unroll
  for (int mt = 0; mt < 4; ++mt)
    #pragma unroll
    for (int r = 0; r < 4; ++r) {
      float v = rm[mt][r];
      v = fmaxf(v, __shfl_xor(v, 1, 64));
      v = fmaxf(v, __shfl_xor(v, 2, 64));
      v = fmaxf(v, __shfl_xor(v, 4, 64));
      v = fmaxf(v, __shfl_xor(v, 8, 64));
      rm[mt][r] = v;
    }
  #pragma unroll
  for (int nt = 0; nt < 4; ++nt) {
    float v = cm[nt];
    v = fmaxf(v, __shfl_xor(v, 16, 64));
    v = fmaxf(v, __shfl_xor(v, 32, 64));
    cm[nt] = v;
  }
  if (lr == 0) {
    #pragma unroll
    for (int mt = 0; mt < 4; ++mt)
      #pragma unroll
      for (int r = 0; r < 4; ++r) redA[wc][64 * wr + mt * 16 + kg * 4 + r] = rm[mt][r];
  }
  if (kg == 0) {
    #pragma unroll
    for (int nt = 0; nt < 4; ++nt) redB[wr][64 * wc + nt * 16 + lr] = cm[nt];
  }
  __syncthreads();
  if (tid < 128) {
    const float o1 = fmaxf(redA[0][tid], redA[1][tid]);
    const float o2 = fmaxf(redB[0][tid], redB[1][tid]);
    const long oi = ((long)b * 128 + tid) * 20 + p;
    out[(long)w * 81920 + oi] = o1;
    out[163840 + (long)w * 81920 + oi] = o2;
  }
}

// ---------------------------------------------------------------------------
extern "C" void kernel_launch(void* const* d_in, const int* in_sizes, int n_in,
                              void* d_out, int out_size, void* d_ws, size_t ws_size,
                              hipStream_t stream) {
  const int* tok1 = (const int*)d_in[0];
  const int* tok2 = (const int*)d_in[1];
  const float* embed = (const float*)d_in[2];
  const float* wih0 = (const float*)d_in[3];
  const float* whh0 = (const float*)d_in[4];
  const float* bih0 = (const float*)d_in[5];
  const float* bhh0 = (const float*)d_in[6];
  const float* wih1 = (const float*)d_in[7];
  const float* whh1 = (const float*)d_in[8];
  const float* bih1 = (const float*)d_in[9];
  const float* bhh1 = (const float*)d_in[10];
  const float* wih2 = (const float*)d_in[11];
  const float* whh2 = (const float*)d_in[12];
  const float* bih2 = (const float*)d_in[13];
  const float* bhh2 = (const float*)d_in[14];
  const float* wih3 = (const float*)d_in[15];
  const float* whh3 = (const float*)d_in[16];
  const float* bih3 = (const float*)d_in[17];
  const float* bhh3 = (const float*)d_in[18];
  const float* W1 = (const float*)d_in[19];
  const float* W2 = (const float*)d_in[20];
  float* out = (float*)d_out;

  char* ws = (char*)d_ws;
  const size_t XPROJ_B = 26214400;   // 4*128*12800*4  (xprojP, permuted)
  const size_t SE_B = 1638400;       // 32*128*200*2
  if (ws_size < XPROJ_B + 2 * SE_B) return;
  float* xprojP = (float*)ws;
  u16* s1e = (u16*)(ws + XPROJ_B);
  u16* s2e = (u16*)(ws + XPROJ_B + SE_B);

  k1_xproj<<<dim3(64, 4, 2), 256, 0, stream>>>(
      tok1, tok2, embed, wih0, wih1, wih2, wih3,
      bih0, bih1, bih2, bih3, bhh0, bhh1, bhh2, bhh3, xprojP);
  k2_lstm<<<dim3(2, 4), 640, 0, stream>>>(xprojP, whh0, whh1, whh2, whh3, s1e, s2e);
  k4_match<<<dim3(32, 20, 2), 256, 0, stream>>>(s1e, s2e, W1, W2, out);
}

// Round 20
// 180.068 us; speedup vs baseline: 1.0432x; 1.0432x over previous
//
#include <hip/hip_runtime.h>
#include <cstddef>

typedef float f32x4 __attribute__((ext_vector_type(4)));
typedef __bf16 bf16x8 __attribute__((ext_vector_type(8)));
typedef unsigned short u16;
typedef unsigned short u16x4 __attribute__((ext_vector_type(4)));

__device__ __forceinline__ u16 f2bf(float f) {
  unsigned u = __builtin_bit_cast(unsigned, f);
  u += 0x7FFFu + ((u >> 16) & 1u);   // RNE round to bf16
  return (u16)(u >> 16);
}
__device__ __forceinline__ float bf2f(u16 b) {
  unsigned u = ((unsigned)b) << 16;
  return __builtin_bit_cast(float, u);
}
__device__ __forceinline__ u16 cvt_bf(float f) {   // native RNE cast
  return __builtin_bit_cast(u16, (__bf16)f);
}
__device__ __forceinline__ float fastrcp(float x) { return __builtin_amdgcn_rcpf(x); }
#if __has_builtin(__builtin_amdgcn_exp2f)
__device__ __forceinline__ float fexp2(float x) { return __builtin_amdgcn_exp2f(x); }
#else
__device__ __forceinline__ float fexp2(float x) { return exp2f(x); }
#endif
#define LOG2E 1.44269504f
#define LOG2E2 2.88539008f

__device__ __forceinline__ void wg_barrier() {
  asm volatile("s_waitcnt lgkmcnt(0)" ::: "memory");
  __builtin_amdgcn_s_barrier();
  __builtin_amdgcn_sched_barrier(0);
}

// ---------------------------------------------------------------------------
// K1 v4 (R18, proven): 64m x 64n per wg, K split 2x160, B-prefetch pipeline.
// ---------------------------------------------------------------------------
#define K1S 168

#define K1_ISSUE_B(C_, KH_)                                                 \
  {                                                                         \
    const int nc_ = z * 4 + (C_);                                           \
    _Pragma("unroll")                                                       \
    for (int it = 0; it < 10; ++it) {                                       \
      const int idx = it * 256 + tid;                                       \
      const int row = idx / 40, kq = idx % 40;                              \
      const int k = (KH_) * 160 + kq * 4;                                   \
      const int j = nc_ * 16 + (row & 15);                                  \
      const int n = (row >> 4) * 100 + j;                                   \
      const bool val = (k < 300 && j < 100);                                \
      const long o_ = val ? ((long)n * 300 + k) : 0;                        \
      breg[it] = *(const f32x4*)(wih + o_);                                 \
    }                                                                       \
  }

#define K1_WRITE_B(C_, KH_)                                                 \
  {                                                                         \
    const int nc_ = z * 4 + (C_);                                           \
    _Pragma("unroll")                                                       \
    for (int it = 0; it < 10; ++it) {                                       \
      const int idx = it * 256 + tid;                                       \
      const int row = idx / 40, kq = idx % 40;                              \
      const int k = (KH_) * 160 + kq * 4;                                   \
      const int j = nc_ * 16 + (row & 15);                                  \
      u16x4 o = {0, 0, 0, 0};                                               \
      if (k < 300 && j < 100) {                                             \
        o[0] = cvt_bf(breg[it][0]); o[1] = cvt_bf(breg[it][1]);             \
        o[2] = cvt_bf(breg[it][2]); o[3] = cvt_bf(breg[it][3]);             \
      }                                                                     \
      *(u16x4*)(bL + row * K1S + kq * 4) = o;                               \
    }                                                                       \
  }

#define K1_MFMA(KH_)                                                        \
  {                                                                         \
    const u16* ak = a0 + (KH_) * 64 * K1S;                                  \
    _Pragma("unroll")                                                       \
    for (int ks = 0; ks < 5; ++ks) {                                        \
      const bf16x8 af = *(const bf16x8*)(ak + ks * 32);                     \
      bf16x8 bfv[4];                                                        \
      _Pragma("unroll")                                                     \
      for (int nt = 0; nt < 4; ++nt)                                        \
        bfv[nt] = *(const bf16x8*)(b0 + nt * 16 * K1S + ks * 32);           \
      _Pragma("unroll")                                                     \
      for (int nt = 0; nt < 4; ++nt)                                        \
        acc[nt] = __builtin_amdgcn_mfma_f32_16x16x32_bf16(af, bfv[nt], acc[nt], 0, 0, 0); \
    }                                                                       \
  }

__global__ __launch_bounds__(256) void k1_xproj(
    const int* __restrict__ tok1, const int* __restrict__ tok2,
    const float* __restrict__ embed,
    const float* __restrict__ wihA, const float* __restrict__ wihB,
    const float* __restrict__ wihC, const float* __restrict__ wihD,
    const float* __restrict__ bihA, const float* __restrict__ bihB,
    const float* __restrict__ bihC, const float* __restrict__ bihD,
    const float* __restrict__ bhhA, const float* __restrict__ bhhB,
    const float* __restrict__ bhhC, const float* __restrict__ bhhD,
    float* __restrict__ xprojP)
{
  __shared__ __align__(16) u16 aL[2 * 64 * K1S];   // 43.0 KB
  __shared__ __align__(16) u16 bL[64 * K1S];       // 21.5 KB
  __shared__ __align__(16) float tp[4096];         // 16.0 KB
  const int mg = blockIdx.x;
  const int dir = blockIdx.y;
  const int z = blockIdx.z;
  const float* wih = (dir == 0) ? wihA : (dir == 1) ? wihB : (dir == 2) ? wihC : wihD;
  const float* bih = (dir == 0) ? bihA : (dir == 1) ? bihB : (dir == 2) ? bihC : bihD;
  const float* bhh = (dir == 0) ? bhhA : (dir == 1) ? bhhB : (dir == 2) ? bhhC : bhhD;
  const int* tok = (dir < 2) ? tok1 : tok2;
  const int tid = threadIdx.x;

  f32x4 breg[10];
  K1_ISSUE_B(0, 0)

  #pragma unroll
  for (int it = 0; it < 20; ++it) {
    const int idx = it * 256 + tid;
    const int row = idx / 80, k = (idx % 80) * 4;
    u16x4 o = {0, 0, 0, 0};
    if (k < 300) {
      const int bb = row & 31, ll = mg * 2 + (row >> 5);
      const long ar = (long)tok[bb * 128 + ll] * 300;
      const f32x4 v = *(const f32x4*)(embed + ar + k);
      o[0] = cvt_bf(v[0]); o[1] = cvt_bf(v[1]); o[2] = cvt_bf(v[2]); o[3] = cvt_bf(v[3]);
    }
    const int kh = k >= 160;
    *(u16x4*)(aL + kh * 64 * K1S + row * K1S + (k - kh * 160)) = o;
  }

  const int lane = tid & 63, w = tid >> 6;
  const int lr = lane & 15, kg = lane >> 4;
  const int lloc = w >> 1;
  const int bloc0 = (w & 1) * 16 + kg * 4;
  const u16* a0 = aL + (w * 16 + lr) * K1S + kg * 8;
  const u16* b0 = bL + lr * K1S + kg * 8;
  const int nch = z ? 3 : 4;

  for (int c = 0; c < nch; ++c) {
    const int nc = z * 4 + c;
    f32x4 acc[4];
    #pragma unroll
    for (int nt = 0; nt < 4; ++nt) acc[nt] = 0.f;

    __syncthreads();
    K1_WRITE_B(c, 0)
    K1_ISSUE_B(c, 1)
    __syncthreads();
    K1_MFMA(0)
    __syncthreads();
    K1_WRITE_B(c, 1)
    if (c + 1 < nch) { K1_ISSUE_B(c + 1, 0) }
    __syncthreads();
    K1_MFMA(1)

    const int jl = nc * 16 + lr;
    float bias[4];
    #pragma unroll
    for (int nt = 0; nt < 4; ++nt)
      bias[nt] = (jl < 100) ? (bih[nt * 100 + jl] + bhh[nt * 100 + jl]) : 0.f;
    #pragma unroll
    for (int rr = 0; rr < 4; ++rr) {
      f32x4 v;
      v[0] = (acc[0][rr] + bias[0]) * LOG2E;
      v[1] = (acc[1][rr] + bias[1]) * LOG2E;
      v[2] = (acc[2][rr] + bias[2]) * LOG2E2;
      v[3] = (acc[3][rr] + bias[3]) * LOG2E;
      const int gran = (lloc * 16 + lr) * 32 + bloc0 + rr;
      *(f32x4*)(tp + gran * 4) = v;
    }
    __syncthreads();

    #pragma unroll
    for (int it = 0; it < 4; ++it) {
      const int idx = it * 256 + tid;
      const int sl = idx >> 9, j = (idx >> 5) & 15, b = idx & 31;
      const int jg = nc * 16 + j;
      const f32x4 v = *(const f32x4*)(tp + idx * 4);
      if (jg < 100)
        *(f32x4*)(xprojP + ((long)(dir * 128 + mg * 2 + sl) * 100 + jg) * 128 + b * 4) = v;
    }
  }
}

// ---------------------------------------------------------------------------
// K2: recurrent LSTM (R18/R17 version, proven: 103 us, unroll-by-4, VGPR 108).
// ---------------------------------------------------------------------------
__device__ __forceinline__ bf16x8 frag_ld(const float* __restrict__ whh,
                                          int mt, int ks, int lr, int kg) {
  bf16x8 f;
  const int orow = (lr & 3) * 100 + mt * 4 + (lr >> 2);
  const float sc = ((lr & 3) == 2) ? LOG2E2 : LOG2E;
  #pragma unroll
  for (int u = 0; u < 8; ++u) {
    const int k = ks * 32 + kg * 8 + u;
    const float v = (mt < 25 && k < 100) ? whh[(long)orow * 100 + k] : 0.f;
    f[u] = (__bf16)(v * sc);
  }
  return f;
}

#define K2_MFMA4(A_, C_, F0_, F1_, F2_, F3_)                                \
  A_ = __builtin_amdgcn_mfma_f32_16x16x32_bf16(F0_, hb0, C_, 0, 0, 0);      \
  A_ = __builtin_amdgcn_mfma_f32_16x16x32_bf16(F1_, hb1, A_, 0, 0, 0);      \
  A_ = __builtin_amdgcn_mfma_f32_16x16x32_bf16(F2_, hb2, A_, 0, 0, 0);      \
  A_ = __builtin_amdgcn_mfma_f32_16x16x32_bf16(F3_, hb3, A_, 0, 0, 0);

#define K2_GATE(A_, CC_, WRO_, WBUF_)                                       \
  {                                                                         \
    const float Ei = fexp2(A_[0]);                                          \
    const float Ef = fexp2(A_[1]);                                          \
    const float Eg = fexp2(A_[2]);                                          \
    const float pf = 1.0f + Ef, pi = 1.0f + Ei, pg = Eg + 1.0f;             \
    const float d_ = fastrcp(pf * pi * pg);                                 \
    CC_ = (Ef * CC_ * pi * pg + Ei * (Eg - 1.0f) * pf) * d_;                \
    const float Eo = fexp2(A_[3]);                                          \
    const float Ec = fexp2(CC_ * LOG2E2);                                   \
    const float h_ = Eo * (Ec - 1.0f) * fastrcp((1.0f + Eo) * (Ec + 1.0f)); \
    *(u16*)(hby + (WRO_) + (WBUF_) * 4096) = f2bf(h_);                      \
  }

#define K2_STEP(RB_, XC0, XC1, XC2, XC3, XP0, XP1, XP2, XP3)                \
  {                                                                         \
    bf16x8 hb0 = *(const bf16x8*)(hby + rd0 + (RB_) * 4096);                \
    bf16x8 hb1 = *(const bf16x8*)(hby + rd1 + (RB_) * 4096);                \
    bf16x8 hb2 = *(const bf16x8*)(hby + rd2 + (RB_) * 4096);                \
    bf16x8 hb3 = *(const bf16x8*)(hby + rd3 + (RB_) * 4096);                \
    XP0 = *(const f32x4*)(pstep + off0);                                    \
    XP1 = *(const f32x4*)(pstep + off1);                                    \
    XP2 = *(const f32x4*)(pstep + off2);                                    \
    if (wave == 0) XP3 = *(const f32x4*)(pstep + off3);                     \
    pstep += dstep;                                                         \
    f32x4 a0, a1, a2, a3;                                                   \
    K2_MFMA4(a0, XC0, f00, f01, f02, f03)                                   \
    K2_MFMA4(a1, XC1, f10, f11, f12, f13)                                   \
    K2_MFMA4(a2, XC2, f20, f21, f22, f23)                                   \
    if (wave == 0) { K2_MFMA4(a3, XC3, f30, f31, f32, f33) }                \
    K2_GATE(a0, cc0, wr0, (RB_) ^ 1)                                        \
    K2_GATE(a1, cc1, wr1, (RB_) ^ 1)                                        \
    K2_GATE(a2, cc2, wr2, (RB_) ^ 1)                                        \
    if (wave == 0) { K2_GATE(a3, cc3, wr3, (RB_) ^ 1) }                     \
  }

#define K2_COPY(TA_, CB_)                                                   \
  if (cact) {                                                               \
    const unsigned v_ = *(const unsigned*)(hby + cprd + (CB_) * 4096);      \
    const unsigned v2_ = *(const unsigned*)(hby + cprd + 2048 + (CB_) * 4096); \
    seD[cpbase + (TA_) * 100] = v_;                                         \
    seD[cpbase2 + (TA_) * 100] = v2_;                                       \
  }

__global__ __launch_bounds__(512, 1) void k2_lstm(
    const float* __restrict__ xprojP,
    const float* __restrict__ whhA, const float* __restrict__ whhB,
    const float* __restrict__ whhC, const float* __restrict__ whhD,
    u16* __restrict__ s1e, u16* __restrict__ s2e)
{
  const int bh = blockIdx.x;
  const int dir = blockIdx.y;
  const float* whh = (dir == 0) ? whhA : (dir == 1) ? whhB : (dir == 2) ? whhC : whhD;
  const int tid = threadIdx.x;
  const int lane = tid & 63, wave = tid >> 6;
  const int lr = lane & 15, kg = lane >> 4;
  const int mt0 = wave, mt1 = wave + 8, mt2 = wave + 16, mt3 = wave + 24;

  __shared__ __align__(16) u16 hraw[2 * 16 * 128];
  char* hby = (char*)hraw;

  bf16x8 f00 = frag_ld(whh, mt0, 0, lr, kg), f01 = frag_ld(whh, mt0, 1, lr, kg),
         f02 = frag_ld(whh, mt0, 2, lr, kg), f03 = frag_ld(whh, mt0, 3, lr, kg);
  bf16x8 f10 = frag_ld(whh, mt1, 0, lr, kg), f11 = frag_ld(whh, mt1, 1, lr, kg),
         f12 = frag_ld(whh, mt1, 2, lr, kg), f13 = frag_ld(whh, mt1, 3, lr, kg);
  bf16x8 f20 = frag_ld(whh, mt2, 0, lr, kg), f21 = frag_ld(whh, mt2, 1, lr, kg),
         f22 = frag_ld(whh, mt2, 2, lr, kg), f23 = frag_ld(whh, mt2, 3, lr, kg);
  bf16x8 f30 = frag_ld(whh, mt3, 0, lr, kg), f31 = frag_ld(whh, mt3, 1, lr, kg),
         f32 = frag_ld(whh, mt3, 2, lr, kg), f33 = frag_ld(whh, mt3, 3, lr, kg);

  for (int idx = tid; idx < 2 * 16 * 128; idx += 512) hraw[idx] = 0;

  const int e7 = lr & 7;
  const int rd0 = lr * 256 + ((kg ^ e7) * 16);
  const int rd1 = lr * 256 + (((4 + kg) ^ e7) * 16);
  const int rd2 = lr * 256 + (((8 + kg) ^ e7) * 16);
  const int rd3 = lr * 256 + (((12 + kg) ^ e7) * 16);
  const int wr0 = lr * 256 + (((mt0 >> 1) ^ e7) * 16) + ((mt0 & 1) * 4 + kg) * 2;
  const int wr1 = lr * 256 + (((mt1 >> 1) ^ e7) * 16) + ((mt1 & 1) * 4 + kg) * 2;
  const int wr2 = lr * 256 + (((mt2 >> 1) ^ e7) * 16) + ((mt2 & 1) * 4 + kg) * 2;
  const int wr3 = lr * 256 + (((mt3 >> 1) ^ e7) * 16) + ((mt3 & 1) * 4 + kg) * 2;

  const bool cact = (tid < 400);
  const int cb = tid / 50, cj2 = tid - cb * 50;
  const int cprd = cb * 256 + (((cj2 >> 2) ^ (cb & 7)) * 16) + (cj2 & 3) * 4;
  const bool bwd = (dir & 1);
  unsigned* seD = (unsigned*)((dir < 2) ? s1e : s2e);
  const long cpbase = ((long)(bh * 16 + cb) * 128) * 100 + (bwd ? 50 : 0) + cj2;
  const long cpbase2 = cpbase + (long)8 * 128 * 100;

  const float* pbase = xprojP + (long)dir * 128 * 12800;
  const int off0 = ((mt0 * 4 + kg) * 32 + bh * 16 + lr) * 4;
  const int off1 = ((mt1 * 4 + kg) * 32 + bh * 16 + lr) * 4;
  const int off2 = ((mt2 * 4 + kg) * 32 + bh * 16 + lr) * 4;
  const int off3 = ((mt3 * 4 + kg) * 32 + bh * 16 + lr) * 4;
  const long dstep = bwd ? -12800 : 12800;
  const float* pstep = pbase + (long)(bwd ? 125 : 2) * 12800;

  f32x4 xa0, xa1, xa2, xa3, xb0, xb1, xb2, xb3;
  f32x4 xc0, xc1, xc2, xc3, xd0, xd1, xd2, xd3;
  {
    const float* p0 = pbase + (long)(bwd ? 127 : 0) * 12800;
    const float* p1 = pbase + (long)(bwd ? 126 : 1) * 12800;
    xa0 = *(const f32x4*)(p0 + off0); xa1 = *(const f32x4*)(p0 + off1);
    xa2 = *(const f32x4*)(p0 + off2);
    xb0 = *(const f32x4*)(p1 + off0); xb1 = *(const f32x4*)(p1 + off1);
    xb2 = *(const f32x4*)(p1 + off2);
    xa3 = xb3 = f32x4{0.f, 0.f, 0.f, 0.f};
    xc0 = xc1 = xc2 = xc3 = f32x4{0.f, 0.f, 0.f, 0.f};
    xd0 = xd1 = xd2 = xd3 = f32x4{0.f, 0.f, 0.f, 0.f};
    if (wave == 0) { xa3 = *(const f32x4*)(p0 + off3); xb3 = *(const f32x4*)(p1 + off3); }
  }
  float cc0 = 0.f, cc1 = 0.f, cc2 = 0.f, cc3 = 0.f;
  __syncthreads();

  #pragma unroll 1
  for (int tt = 0; tt < 32; ++tt) {
    const int i0 = 4 * tt;
    K2_STEP(0, xa0, xa1, xa2, xa3, xc0, xc1, xc2, xc3)
    wg_barrier();
    K2_COPY(bwd ? 127 - i0 : i0, 1)
    K2_STEP(1, xb0, xb1, xb2, xb3, xd0, xd1, xd2, xd3)
    wg_barrier();
    K2_COPY(bwd ? 126 - i0 : i0 + 1, 0)
    K2_STEP(0, xc0, xc1, xc2, xc3, xa0, xa1, xa2, xa3)
    wg_barrier();
    K2_COPY(bwd ? 125 - i0 : i0 + 2, 1)
    K2_STEP(1, xd0, xd1, xd2, xd3, xb0, xb1, xb2, xb3)
    wg_barrier();
    K2_COPY(bwd ? 124 - i0 : i0 + 3, 0)
  }
}

// ---------------------------------------------------------------------------
// K4 v2 (R16, proven): matching + fused norms, K-split, 2 wg/CU.
// ---------------------------------------------------------------------------
#define K4S 136
__global__ __launch_bounds__(256, 2) void k4_match(
    const u16* __restrict__ s1e, const u16* __restrict__ s2e,
    const float* __restrict__ W1, const float* __restrict__ W2,
    float* __restrict__ out)
{
  __shared__ __align__(16) u16 aLb[128 * K4S];
  __shared__ __align__(16) u16 bLb[128 * K4S];
  __shared__ float rnuL[128], rnvL[128];
  __shared__ float redA[2][128], redB[2][128];
  const int b = blockIdx.x, p = blockIdx.y, w = blockIdx.z;
  const int tid = threadIdx.x;
  const float* Wp = (w ? W2 : W1) + p * 200;
  const u16* s1r = s1e + (long)b * 128 * 200;
  const u16* s2r = s2e + (long)b * 128 * 200;

  const int lane = tid & 63, wvid = tid >> 6;
  const int wr = wvid >> 1, wc = wvid & 1;
  const int lr = lane & 15, kg = lane >> 4;
  const u16* a0 = aLb + (64 * wr + lr) * K4S + kg * 8;
  const u16* b0 = bLb + (64 * wc + lr) * K4S + kg * 8;

  f32x4 acc[4][4];
  #pragma unroll
  for (int mt = 0; mt < 4; ++mt)
    #pragma unroll
    for (int nt = 0; nt < 4; ++nt) acc[mt][nt] = 0.f;
  float nacc = 0.f;
  const int nrow = tid & 127;
  const u16* nsrc = (tid < 128) ? (aLb + nrow * K4S) : (bLb + nrow * K4S);

  #pragma unroll
  for (int ch = 0; ch < 2; ++ch) {
    const int k0 = ch * 128;
    const int NQ = ch ? 24 : 32;
    for (int idx = tid; idx < 128 * NQ; idx += 256) {
      const int row = idx / NQ;
      const int kq = idx - row * NQ;
      const int k = k0 + kq * 4;
      u16x4 oa = {0, 0, 0, 0}, ob = {0, 0, 0, 0};
      if (k < 200) {
        const u16x4 sa = *(const u16x4*)(s1r + row * 200 + k);
        const u16x4 sb = *(const u16x4*)(s2r + row * 200 + k);
        const f32x4 wv = *(const f32x4*)(Wp + k);
        #pragma unroll
        for (int u = 0; u < 4; ++u) {
          oa[u] = cvt_bf(bf2f(sa[u]) * wv[u]);
          ob[u] = cvt_bf(bf2f(sb[u]) * wv[u]);
        }
      }
      *(u16x4*)(aLb + row * K4S + kq * 4) = oa;
      *(u16x4*)(bLb + row * K4S + kq * 4) = ob;
    }
    __syncthreads();

    {
      const int nq8 = ch ? 12 : 16;
      #pragma unroll 4
      for (int q = 0; q < nq8; ++q) {
        const bf16x8 v = *(const bf16x8*)(nsrc + q * 8);
        #pragma unroll
        for (int u = 0; u < 8; ++u) {
          const float f = (float)v[u];
          nacc += f * f;
        }
      }
    }
    const int nks = ch ? 3 : 4;
    for (int ks = 0; ks < nks; ++ks) {
      bf16x8 af[4], bfv[4];
      #pragma unroll
      for (int mt = 0; mt < 4; ++mt) af[mt] = *(const bf16x8*)(a0 + mt * 16 * K4S + ks * 32);
      #pragma unroll
      for (int nt = 0; nt < 4; ++nt) bfv[nt] = *(const bf16x8*)(b0 + nt * 16 * K4S + ks * 32);
      #pragma unroll
      for (int mt = 0; mt < 4; ++mt)
        #pragma unroll
        for (int nt = 0; nt < 4; ++nt)
          acc[mt][nt] = __builtin_amdgcn_mfma_f32_16x16x32_bf16(af[mt], bfv[nt], acc[mt][nt], 0, 0, 0);
    }
    __syncthreads();
  }

  {
    const float rv = 1.f / fmaxf(sqrtf(nacc), 1e-8f);
    if (tid < 128) rnuL[nrow] = rv; else rnvL[nrow] = rv;
  }
  __syncthreads();

  float ru[4][4], rm[4][4], rv[4], cm[4];
  #pragma unroll
  for (int mt = 0; mt < 4; ++mt)
    #pragma unroll
    for (int r = 0; r < 4; ++r) {
      ru[mt][r] = rnuL[64 * wr + mt * 16 + kg * 4 + r];
      rm[mt][r] = -3.0e38f;
    }
  #pragma unroll
  for (int nt = 0; nt < 4; ++nt) { rv[nt] = rnvL[64 * wc + nt * 16 + lr]; cm[nt] = -3.0e38f; }
  #pragma unroll
  for (int mt = 0; mt < 4; ++mt)
    #pragma unroll
    for (int nt = 0; nt < 4; ++nt)
      #pragma unroll
      for (int r = 0; r < 4; ++r) {
        const float v = acc[mt][nt][r] * ru[mt][r] * rv[nt];
        rm[mt][r] = fmaxf(rm[mt][r], v);
        cm[nt] = fmaxf(cm[nt], v);
      }
  #pragma unroll
  for (int mt = 0; mt < 4; ++mt)
    #pragma unroll
    for (int r = 0; r < 4; ++r) {
      float v = rm[mt][r];
      v = fmaxf(v, __shfl_xor(v, 1, 64));
      v = fmaxf(v, __shfl_xor(v, 2, 64));
      v = fmaxf(v, __shfl_xor(v, 4, 64));
      v = fmaxf(v, __shfl_xor(v, 8, 64));
      rm[mt][r] = v;
    }
  #pragma unroll
  for (int nt = 0; nt < 4; ++nt) {
    float v = cm[nt];
    v = fmaxf(v, __shfl_xor(v, 16, 64));
    v = fmaxf(v, __shfl_xor(v, 32, 64));
    cm[nt] = v;
  }
  if (lr == 0) {
    #pragma unroll
    for (int mt = 0; mt < 4; ++mt)
      #pragma unroll
      for (int r = 0; r < 4; ++r) redA[wc][64 * wr + mt * 16 + kg * 4 + r] = rm[mt][r];
  }
  if (kg == 0) {
    #pragma unroll
    for (int nt = 0; nt < 4; ++nt) redB[wr][64 * wc + nt * 16 + lr] = cm[nt];
  }
  __syncthreads();
  if (tid < 128) {
    const float o1 = fmaxf(redA[0][tid], redA[1][tid]);
    const float o2 = fmaxf(redB[0][tid], redB[1][tid]);
    const long oi = ((long)b * 128 + tid) * 20 + p;
    out[(long)w * 81920 + oi] = o1;
    out[163840 + (long)w * 81920 + oi] = o2;
  }
}

// ---------------------------------------------------------------------------
extern "C" void kernel_launch(void* const* d_in, const int* in_sizes, int n_in,
                              void* d_out, int out_size, void* d_ws, size_t ws_size,
                              hipStream_t stream) {
  const int* tok1 = (const int*)d_in[0];
  const int* tok2 = (const int*)d_in[1];
  const float* embed = (const float*)d_in[2];
  const float* wih0 = (const float*)d_in[3];
  const float* whh0 = (const float*)d_in[4];
  const float* bih0 = (const float*)d_in[5];
  const float* bhh0 = (const float*)d_in[6];
  const float* wih1 = (const float*)d_in[7];
  const float* whh1 = (const float*)d_in[8];
  const float* bih1 = (const float*)d_in[9];
  const float* bhh1 = (const float*)d_in[10];
  const float* wih2 = (const float*)d_in[11];
  const float* whh2 = (const float*)d_in[12];
  const float* bih2 = (const float*)d_in[13];
  const float* bhh2 = (const float*)d_in[14];
  const float* wih3 = (const float*)d_in[15];
  const float* whh3 = (const float*)d_in[16];
  const float* bih3 = (const float*)d_in[17];
  const float* bhh3 = (const float*)d_in[18];
  const float* W1 = (const float*)d_in[19];
  const float* W2 = (const float*)d_in[20];
  float* out = (float*)d_out;

  char* ws = (char*)d_ws;
  const size_t XPROJ_B = 26214400;   // 4*128*12800*4  (xprojP, permuted)
  const size_t SE_B = 1638400;       // 32*128*200*2
  if (ws_size < XPROJ_B + 2 * SE_B) return;
  float* xprojP = (float*)ws;
  u16* s1e = (u16*)(ws + XPROJ_B);
  u16* s2e = (u16*)(ws + XPROJ_B + SE_B);

  k1_xproj<<<dim3(64, 4, 2), 256, 0, stream>>>(
      tok1, tok2, embed, wih0, wih1, wih2, wih3,
      bih0, bih1, bih2, bih3, bhh0, bhh1, bhh2, bhh3, xprojP);
  k2_lstm<<<dim3(2, 4), 512, 0, stream>>>(xprojP, whh0, whh1, whh2, whh3, s1e, s2e);
  k4_match<<<dim3(32, 20, 2), 256, 0, stream>>>(s1e, s2e, W1, W2, out);
}